// Round 3
// baseline (160.618 us; speedup 1.0000x reference)
//
#include <hip/hip_runtime.h>
#include <stdint.h>
#include <float.h>

#define NREGION 512
#define IN_CH 128
#define E_GRAPH 16384
#define NEDGE (NREGION*NREGION)

// ---- workspace layout (bytes) ----
#define OFF_DEG   0                               // 512 int32
#define OFF_DINV  2048                            // 512 f32
#define OFF_H     4096                            // 65536 f32
#define OFF_ACC   (OFF_H   + NREGION*IN_CH*4)
#define OFF_X     (OFF_ACC + NREGION*IN_CH*4)
#define OFF_P     (OFF_X   + NREGION*IN_CH*4)
#define OFF_Q     (OFF_P   + NREGION*IN_CH*4)
#define OFF_LP    (OFF_Q   + NREGION*IN_CH*4)     // 1 double

// ---------------- threefry2x32 (random123 / JAX) ----------------
__host__ __device__ __forceinline__ void tf2x32(uint32_t k0, uint32_t k1,
    uint32_t x0, uint32_t x1, uint32_t& o0, uint32_t& o1){
  uint32_t ks2 = k0 ^ k1 ^ 0x1BD11BDAu;
  x0 += k0; x1 += k1;
#define TFR(r) { x0 += x1; x1 = (x1<<(r))|(x1>>(32-(r))); x1 ^= x0; }
  TFR(13) TFR(15) TFR(26) TFR(6)
  x0 += k1; x1 += ks2 + 1u;
  TFR(17) TFR(29) TFR(16) TFR(24)
  x0 += ks2; x1 += k0 + 2u;
  TFR(13) TFR(15) TFR(26) TFR(6)
  x0 += k0; x1 += k1 + 3u;
  TFR(17) TFR(29) TFR(16) TFR(24)
  x0 += k1; x1 += ks2 + 4u;
  TFR(13) TFR(15) TFR(26) TFR(6)
  x0 += ks2; x1 += k0 + 5u;
#undef TFR
  o0 = x0; o1 = x1;
}

// JAX partitionable scheme:
//   split(k, n)[i]    = TF(k; hi=0, lo=i)
//   random_bits (u32) = out0 ^ out1 of TF(k; 0, counter)
__device__ __forceinline__ float bits_to_u01(uint32_t bits){
  #pragma clang fp contract(off)
  return __uint_as_float((bits >> 9) | 0x3F800000u) - 1.0f;
}
__device__ __forceinline__ float unif01(uint32_t k0, uint32_t k1){
  uint32_t a, b; tf2x32(k0,k1,0u,0u,a,b);
  return bits_to_u01(a ^ b);
}

// XLA ErfInv32 (Giles polynomial)
__device__ __forceinline__ float erfinv_xla(float x){
  #pragma clang fp contract(off)
  float xx = x*x;
  float w = -log1pf(-xx);
  float p;
  if (w < 5.0f){
    w = w - 2.5f;
    p = 2.81022636e-08f;
    p = 3.43273939e-07f + p*w;
    p = -3.5233877e-06f + p*w;
    p = -4.39150654e-06f + p*w;
    p = 0.00021858087f  + p*w;
    p = -0.00125372503f + p*w;
    p = -0.00417768164f + p*w;
    p = 0.246640727f    + p*w;
    p = 1.50140941f     + p*w;
  } else {
    w = sqrtf(w) - 3.0f;
    p = -0.000200214257f;
    p = 0.000100950558f + p*w;
    p = 0.00134934322f  + p*w;
    p = -0.00367342844f + p*w;
    p = 0.00573950773f  + p*w;
    p = -0.0076224613f  + p*w;
    p = 0.00943887047f  + p*w;
    p = 1.00167406f     + p*w;
    p = 2.83297682f     + p*w;
  }
  return p*x;
}

__device__ __forceinline__ float normal01(uint32_t k0, uint32_t k1){
  #pragma clang fp contract(off)
  uint32_t a, b; tf2x32(k0,k1,0u,0u,a,b);
  float f = bits_to_u01(a ^ b);
  const float lo = __uint_as_float(0xBF7FFFFFu);   // nextafter(-1, 0)
  float u = f*2.0f + lo;
  u = fmaxf(lo, u);
  return __uint_as_float(0x3FB504F3u) * erfinv_xla(u);  // f32(sqrt(2))
}

// jax.random.loggamma single draw (Marsaglia-Tsang, log-space).
// Iteration caps (64 outer / 256 inner) are pure hang-guards: acceptance
// prob is >=95%/iter, so P(hit cap) < 1e-80 — observably identical.
__device__ float sample_loggamma(uint32_t ek0, uint32_t ek1, float alpha_orig){
  #pragma clang fp contract(off)
  const float one_third = (float)(1.0/3.0);
  bool boost = (alpha_orig >= 1.0f);
  float alpha = boost ? alpha_orig : (alpha_orig + 1.0f);
  float d = alpha - one_third;
  float c = one_third / sqrtf(d);
  uint32_t key0,key1, sk0,sk1;
  tf2x32(ek0,ek1,0u,0u,key0,key1);
  tf2x32(ek0,ek1,0u,1u,sk0,sk1);
  float u_boost = unif01(sk0,sk1);
  float V = 1.0f;
  for(int it=0; it<64; ++it){
    uint32_t nk0,nk1, xk0,xk1, uk0,uk1;
    tf2x32(key0,key1,0u,0u,nk0,nk1);
    tf2x32(key0,key1,0u,1u,xk0,xk1);
    tf2x32(key0,key1,0u,2u,uk0,uk1);
    float x = 0.0f, v = -1.0f;
    for(int jt=0; jt<256; ++jt){
      uint32_t a0,a1, s0,s1;
      tf2x32(xk0,xk1,0u,0u,a0,a1);
      tf2x32(xk0,xk1,0u,1u,s0,s1);
      x = normal01(s0,s1);
      v = 1.0f + c*x;
      if (v > 0.0f) break;
      xk0=a0; xk1=a1;
    }
    float X  = x*x;
    float vv = v*v;
    V = vv*v;
    float U = unif01(uk0,uk1);
    bool cont = (U >= 1.0f - 0.0331f*(X*X));
    if (cont){
      float thr = X*0.5f + d*((1.0f - V) + logf(V));
      cont = (logf(U) >= thr);
    }
    if (!cont) break;
    key0=nk0; key1=nk1;
  }
  float lg = logf(d) + logf(V);
  if (!boost && (u_boost != 0.0f)) lg = lg + logf(u_boost)*(1.0f/alpha_orig);
  return lg;
}

__device__ __forceinline__ float softplus_xla(float z){
  #pragma clang fp contract(off)
  return fmaxf(z, 0.0f) + log1pf(expf(-fabsf(z)));
}

// XLA Lgamma (Lanczos, g=7, n=8) with reflection for x < 0.5
__device__ float lgamma_xla(float input){
  #pragma clang fp contract(off)
  const float log_sqrt_two_pi = 0.9189385332046727f;
  const float log_pi = 1.1447298858494002f;
  bool reflect = (input < 0.5f);
  float z = reflect ? (0.0f - input) : (input - 1.0f);
  float sum = 1.0f;
  sum = sum + (float)676.520368121885098567009190444019  / (z + 1.0f);
  sum = sum + (float)-1259.13921672240287047156078755283 / (z + 2.0f);
  sum = sum + (float)771.3234287776530788486528258894    / (z + 3.0f);
  sum = sum + (float)-176.61502916214059906584551354     / (z + 4.0f);
  sum = sum + (float)12.507343278686904814458936853      / (z + 5.0f);
  sum = sum + (float)-0.13857109526572011689554707       / (z + 6.0f);
  sum = sum + (float)9.984369578019570859563e-6          / (z + 7.0f);
  sum = sum + (float)1.50563273514931155834e-7           / (z + 8.0f);
  float t = 7.5f + z;
  float log_t = 2.0149030205422647f + log1pf(z / 7.5f);
  float log_y = log_sqrt_two_pi + (z + 0.5f - t/log_t)*log_t + logf(sum);
  if (reflect){
    float abs_in = fabsf(input);
    float frac = abs_in - floorf(abs_in);
    float rfrac = (frac > 0.5f) ? (1.0f - frac) : frac;
    float refl_den = logf(sinf(3.14159265358979323846f * rfrac));
    float r;
    if (isfinite(refl_den)) r = log_pi - refl_den - log_y;
    else r = -refl_den;
    return r;
  }
  return log_y;
}

// ---------------- kernels ----------------
__global__ void k_init(float* acc, int* deg, double* lp){
  int i = blockIdx.x*256 + threadIdx.x;
  if (i < NREGION*IN_CH) acc[i] = 0.0f;
  int j = i - NREGION*IN_CH;
  if (j >= 0 && j < NREGION) deg[j] = 0;
  if (j == NREGION) *lp = 0.0;
}

__global__ void k_deg(const int* __restrict__ ei, int* deg){
  int e = blockIdx.x*256 + threadIdx.x;
  atomicAdd(&deg[ei[E_GRAPH + e]], 1);
}

__global__ void k_dinv(const int* __restrict__ deg, float* dinv){
  int i = blockIdx.x*256 + threadIdx.x;
  if (i < NREGION) dinv[i] = rsqrtf((float)(deg[i] + 1));
}

__global__ void k_h(const float* __restrict__ state, const float* __restrict__ w,
                    float* __restrict__ h){
  __shared__ float row[IN_CH];
  int r = blockIdx.x, c = threadIdx.x;
  row[c] = state[r*IN_CH + c];
  __syncthreads();
  float acc = 0.0f;
  #pragma unroll 8
  for (int k=0;k<IN_CH;k++) acc = fmaf(row[k], w[k*IN_CH + c], acc);
  h[r*IN_CH + c] = acc;
}

__global__ __launch_bounds__(256) void k_scatter(const int* __restrict__ ei,
    const float* __restrict__ h, const float* __restrict__ dinv, float* acc){
  int gid = blockIdx.x*256 + threadIdx.x;
  int e = gid >> 7, f = gid & 127;
  int s = ei[e], d = ei[E_GRAPH + e];
  float norm = dinv[s]*dinv[d];
  atomicAdd(&acc[d*IN_CH + f], h[s*IN_CH + f]*norm);
}

__global__ void k_xfin(const float* __restrict__ acc, const float* __restrict__ h,
                       const float* __restrict__ dinv, const float* __restrict__ cb,
                       const float* __restrict__ state, float* __restrict__ x){
  #pragma clang fp contract(off)
  int i = blockIdx.x*256 + threadIdx.x;
  int r = i >> 7, c = i & 127;
  float di = dinv[r];
  float v = acc[i] + h[i]*(di*di) + cb[c];
  v = fmaxf(v, 0.0f);
  x[i] = v + state[i];
}

__global__ void k_pq(const float* __restrict__ x, const float* __restrict__ w1,
                     float* __restrict__ P, float* __restrict__ Q){
  __shared__ float row[IN_CH];
  int r = blockIdx.x, c = threadIdx.x;
  row[c] = x[r*IN_CH + c];
  __syncthreads();
  float p = 0.0f, q = 0.0f;
  #pragma unroll 8
  for (int k=0;k<IN_CH;k++){
    float xv = row[k];
    p = fmaf(xv, w1[k*IN_CH + c], p);
    q = fmaf(xv, w1[(IN_CH + k)*IN_CH + c], q);
  }
  P[r*IN_CH + c] = p;
  Q[r*IN_CH + c] = q;
}

__global__ __launch_bounds__(256) void k_edge(
    const float* __restrict__ P, const float* __restrict__ Q,
    const int* __restrict__ edges,
    const float* __restrict__ b1, const float* __restrict__ w2,
    const float* __restrict__ b2,
    float* __restrict__ out_action, double* __restrict__ lp_acc,
    uint32_t ka0, uint32_t ka1, uint32_t kb0, uint32_t kb1)
{
  #pragma clang fp contract(off)
  __shared__ float sb1[IN_CH];
  __shared__ float sw2[2*IN_CH];
  __shared__ float sb2[2];
  __shared__ double red[256];
  int t = threadIdx.x;
  if (t < IN_CH) sb1[t] = b1[t];
  sw2[t] = w2[t];
  if (t < 2) sb2[t] = b2[t];
  __syncthreads();
  int e = blockIdx.x*256 + t;
  int s  = edges[2*e];
  int dd = edges[2*e + 1];
  const float4* Ps = (const float4*)(P + s*IN_CH);
  const float4* Qd = (const float4*)(Q + dd*IN_CH);
  float z0 = 0.0f, z1 = 0.0f;
  #pragma unroll 8
  for (int j=0;j<IN_CH/4;j++){
    float4 p = Ps[j], q = Qd[j];
    float h0 = p.x + q.x + sb1[4*j+0]; h0 = (h0 >= 0.0f) ? h0 : 0.01f*h0;
    float h1 = p.y + q.y + sb1[4*j+1]; h1 = (h1 >= 0.0f) ? h1 : 0.01f*h1;
    float h2 = p.z + q.z + sb1[4*j+2]; h2 = (h2 >= 0.0f) ? h2 : 0.01f*h2;
    float h3 = p.w + q.w + sb1[4*j+3]; h3 = (h3 >= 0.0f) ? h3 : 0.01f*h3;
    z0 = fmaf(h0, sw2[(4*j+0)*2+0], z0); z1 = fmaf(h0, sw2[(4*j+0)*2+1], z1);
    z0 = fmaf(h1, sw2[(4*j+1)*2+0], z0); z1 = fmaf(h1, sw2[(4*j+1)*2+1], z1);
    z0 = fmaf(h2, sw2[(4*j+2)*2+0], z0); z1 = fmaf(h2, sw2[(4*j+2)*2+1], z1);
    z0 = fmaf(h3, sw2[(4*j+3)*2+0], z0); z1 = fmaf(h3, sw2[(4*j+3)*2+1], z1);
  }
  z0 = z0 + sb2[0];
  z1 = z1 + sb2[1];
  float a = softplus_xla(z0) + 1e-10f;
  float b = softplus_xla(z1) + 1e-10f;
  uint32_t ea0,ea1, eb0,eb1;
  tf2x32(ka0,ka1, 0u, (uint32_t)e, ea0,ea1);
  tf2x32(kb0,kb1, 0u, (uint32_t)e, eb0,eb1);
  float lga = sample_loggamma(ea0,ea1, a);
  float lgb = sample_loggamma(eb0,eb1, b);
  float lmax = fmaxf(lga, lgb);
  float ga = expf(lga - lmax);
  float gb = expf(lgb - lmax);
  float act = ga / (ga + gb);
  out_action[e] = act;
  // NaN-safe log_prob: clamp act away from exact 0/1 for the log terms.
  // At f32, act saturates whenever |lga-lgb| > ~17; log(0) = -inf would
  // poison the f64 sum (inf + -inf = NaN). Raw act still goes to output.
  float act_c = fminf(fmaxf(act, FLT_MIN), 0.99999994f);  // [2^-126, 1-2^-24]
  float t1 = (a - 1.0f)*logf(act_c);
  float t2 = (b - 1.0f)*log1pf(-act_c);
  float t3 = (lgamma_xla(a) + lgamma_xla(b)) - lgamma_xla(a + b);
  float lp = (t1 + t2) - t3;
  red[t] = (double)lp;
  __syncthreads();
  for (int ofs = 128; ofs > 0; ofs >>= 1){
    if (t < ofs) red[t] += red[t + ofs];
    __syncthreads();
  }
  if (t == 0) atomicAdd(lp_acc, red[0]);
}

__global__ void k_final(const double* __restrict__ lp, float* out){
  if (blockIdx.x == 0 && threadIdx.x == 0) out[NEDGE] = (float)(*lp);
}

// ---------------- launcher ----------------
extern "C" void kernel_launch(void* const* d_in, const int* in_sizes, int n_in,
                              void* d_out, int out_size, void* d_ws, size_t ws_size,
                              hipStream_t stream){
  (void)in_sizes; (void)n_in; (void)out_size; (void)ws_size;
  const float* state  = (const float*)d_in[0];
  const float* conv_w = (const float*)d_in[1];
  const float* conv_b = (const float*)d_in[2];
  const float* lin1_w = (const float*)d_in[3];
  const float* lin1_b = (const float*)d_in[4];
  const float* lin2_w = (const float*)d_in[5];
  const float* lin2_b = (const float*)d_in[6];
  const int* edge_index = (const int*)d_in[7];
  const int* edges      = (const int*)d_in[8];
  float* out = (float*)d_out;

  char* ws = (char*)d_ws;
  int*    deg  = (int*)   (ws + OFF_DEG);
  float*  dinv = (float*) (ws + OFF_DINV);
  float*  h    = (float*) (ws + OFF_H);
  float*  acc  = (float*) (ws + OFF_ACC);
  float*  x    = (float*) (ws + OFF_X);
  float*  P    = (float*) (ws + OFF_P);
  float*  Q    = (float*) (ws + OFF_Q);
  double* lp   = (double*)(ws + OFF_LP);

  uint32_t ka0,ka1, kb0,kb1;
  tf2x32(0u, 42u, 0u, 0u, ka0, ka1);
  tf2x32(0u, 42u, 0u, 1u, kb0, kb1);

  k_init   <<<259, 256, 0, stream>>>(acc, deg, lp);
  k_deg    <<<E_GRAPH/256, 256, 0, stream>>>(edge_index, deg);
  k_dinv   <<<2, 256, 0, stream>>>(deg, dinv);
  k_h      <<<NREGION, IN_CH, 0, stream>>>(state, conv_w, h);
  k_scatter<<<(E_GRAPH*IN_CH)/256, 256, 0, stream>>>(edge_index, h, dinv, acc);
  k_xfin   <<<(NREGION*IN_CH)/256, 256, 0, stream>>>(acc, h, dinv, conv_b, state, x);
  k_pq     <<<NREGION, IN_CH, 0, stream>>>(x, lin1_w, P, Q);
  k_edge   <<<NEDGE/256, 256, 0, stream>>>(P, Q, edges, lin1_b, lin2_w, lin2_b,
                                           out, lp, ka0, ka1, kb0, kb1);
  k_final  <<<1, 64, 0, stream>>>(lp, out);
}